// Round 6
// baseline (938.998 us; speedup 1.0000x reference)
//
#include <hip/hip_runtime.h>

// ---------------------------------------------------------------------------
// DecoderRNN: 256-step LSTM(3) + Bahdanau attention + MLP head, batch=1.
// Round 5b: 20 recurrence WGs (4 h-WGs/layer + 4 x-WGs per upper layer,
// tagged-u64 handoffs, depth-16 x-rings) + 236 tail WGs (counter-gated,
// tag-verified per-t attention+MLP). Fast 2-kernel prep. Grid=256 (1 WG/CU).
// ---------------------------------------------------------------------------

#define VOCAB  47
#define NSTEP  256
#define NREC   20
#define NTAIL  236
#define NMEGA  (NREC + NTAIL)

typedef unsigned long long u64;

// workspace layout (float offsets)
#define F_PROG  16                        // u32[4] L3 progress counters
#define F_H0A   64                        // u64[257][256] tagged h0 history
#define F_H1A   (F_H0A + 131584)
#define F_H2A   (F_H1A + 131584)
#define F_X1    (F_H2A + 131584)          // [256][1024] L1 input gates (+biases)
#define F_VB    (F_X1 + 262144)           // [1024][256] att_V@encT + att_b
#define F_W1T   (F_VB + 262144)           // [512][256]
#define F_W2T   (F_W1T + 131072)          // [256][256]
#define F_W3T   (F_W2T + 65536)           // [256][47]
#define F_AWT   (F_W3T + 12032)           // [256][256] att_W^T
#define F_OVL   (F_AWT + 65536)           // overlay: prep W1iT/AVT, mega G-rings
#define F_W1iT  F_OVL                     // [256][1024] Wih1^T (prep only)
#define F_AVT   (F_OVL + 262144)          // [256][256] attV^T (prep only)
#define F_G2X   F_OVL                     // u64[16][1024] ring (mega)
#define F_G3X   (F_OVL + 32768)           // u64[16][1024] ring (mega)

// tail LDS carve (floats)
#define T_H2  0
#define T_WS  256
#define T_WSP 512
#define T_EX  1024
#define T_CAT 2048
#define T_O1  2560
#define T_O2  2816
#define T_AV  3072
#define T_RED 3328

__device__ __forceinline__ float fma4(float4 w, float4 h, float acc) {
    acc = fmaf(w.x, h.x, acc); acc = fmaf(w.y, h.y, acc);
    acc = fmaf(w.z, h.z, acc); acc = fmaf(w.w, h.w, acc);
    return acc;
}
__device__ __forceinline__ float sigm(float x) {
    return __builtin_amdgcn_rcpf(1.f + __expf(-x));
}
__device__ __forceinline__ float tanh_(float x) {
    float e = __expf(2.f * x);
    return 1.f - 2.f * __builtin_amdgcn_rcpf(e + 1.f);
}
__device__ __forceinline__ void tagstore(u64* p, float v, unsigned tag) {
    u64 pk = ((u64)tag << 32) | (u64)__float_as_uint(v);
    __hip_atomic_store(p, pk, __ATOMIC_RELAXED, __HIP_MEMORY_SCOPE_AGENT);
}
__device__ __forceinline__ float pollval(u64* p, unsigned tag) {
    u64 v;
    do { v = __hip_atomic_load(p, __ATOMIC_RELAXED, __HIP_MEMORY_SCOPE_AGENT); }
    while ((unsigned)(v >> 32) != tag);
    return __uint_as_float((unsigned)(v & 0xffffffffull));
}

// ---------------------------------------------------------------------------
// prep0: 6 transposes + tag/counter init.  593 WGs x 256.
// ---------------------------------------------------------------------------
__global__ __launch_bounds__(256) void prep0_kernel(
    const float* __restrict__ Wih1, const float* __restrict__ attV,
    const float* __restrict__ w1, const float* __restrict__ w2,
    const float* __restrict__ w3, const float* __restrict__ attW,
    const float* __restrict__ h, float* __restrict__ wsf)
{
    __shared__ float tile[32 * 33];
    const int id = blockIdx.x, tid = threadIdx.x;
    if (id == 592) {
        tagstore((u64*)(wsf + F_H0A) + tid, h[tid],       1u);
        tagstore((u64*)(wsf + F_H1A) + tid, h[256 + tid], 1u);
        tagstore((u64*)(wsf + F_H2A) + tid, h[512 + tid], 1u);
        if (tid < 4) ((unsigned*)(wsf + F_PROG))[tid] = 1u;
        return;
    }
    const float* in; float* out; int rows, cols, bxi, byi;
    if (id < 256)      { in = Wih1; out = wsf + F_W1iT; rows = 1024; cols = 256; bxi = id & 7;          byi = id >> 3; }
    else if (id < 320) { in = attV; out = wsf + F_AVT;  rows = 256;  cols = 256; bxi = (id - 256) & 7;  byi = (id - 256) >> 3; }
    else if (id < 448) { in = w1;   out = wsf + F_W1T;  rows = 256;  cols = 512; bxi = (id - 320) & 15; byi = (id - 320) >> 4; }
    else if (id < 512) { in = w2;   out = wsf + F_W2T;  rows = 256;  cols = 256; bxi = (id - 448) & 7;  byi = (id - 448) >> 3; }
    else if (id < 528) { in = w3;   out = wsf + F_W3T;  rows = VOCAB;cols = 256; bxi = (id - 512) & 7;  byi = (id - 512) >> 3; }
    else               { in = attW; out = wsf + F_AWT;  rows = 256;  cols = 256; bxi = (id - 528) & 7;  byi = (id - 528) >> 3; }
    const int tx = tid & 31, ty = tid >> 5;
    const int bx = bxi * 32, by = byi * 32;
    int x = bx + tx;
#pragma unroll
    for (int jj = ty; jj < 32; jj += 8) {
        int y = by + jj;
        if (x < cols && y < rows) tile[jj * 33 + tx] = in[(size_t)y * cols + x];
    }
    __syncthreads();
    x = by + tx;
#pragma unroll
    for (int jj = ty; jj < 32; jj += 8) {
        int y = bx + jj;
        if (x < rows && y < cols) out[(size_t)y * rows + x] = tile[tx * 33 + jj];
    }
}

// ---------------------------------------------------------------------------
// prep1: X1 = emb[Y] @ Wih1^T + b (32 WGs, 8 t each); VB = enc @ attV^T + b
// (128 WGs, 8 s each). Coalesced weight reads, LDS-broadcast activations.
// ---------------------------------------------------------------------------
__global__ __launch_bounds__(256) void prep1_kernel(
    const int* __restrict__ Y, const float* __restrict__ emb,
    const float* __restrict__ bih1, const float* __restrict__ bhh1,
    const float* __restrict__ enc, const float* __restrict__ attB,
    float* __restrict__ wsf)
{
    __shared__ float As[8 * 256];
    __shared__ int ys[8];
    const int id = blockIdx.x, tid = threadIdx.x;
    if (id < 32) {
        const int t0 = id * 8;
        if (tid < 8) ys[tid] = Y[t0 + tid];
        __syncthreads();
#pragma unroll
        for (int q = 0; q < 8; ++q) As[q * 256 + tid] = emb[(size_t)ys[q] * 256 + tid];
        __syncthreads();
        const float* W1iT = wsf + F_W1iT;
        float* X1 = wsf + F_X1;
        for (int cch = 0; cch < 4; ++cch) {
            const int j = cch * 256 + tid;
            float bb = bih1[j] + bhh1[j];
            float acc[8] = {0.f, 0.f, 0.f, 0.f, 0.f, 0.f, 0.f, 0.f};
#pragma unroll 4
            for (int k = 0; k < 256; ++k) {
                float wv2 = W1iT[(size_t)k * 1024 + j];
#pragma unroll
                for (int q = 0; q < 8; ++q) acc[q] = fmaf(As[q * 256 + k], wv2, acc[q]);
            }
#pragma unroll
            for (int q = 0; q < 8; ++q) X1[(size_t)(t0 + q) * 1024 + j] = acc[q] + bb;
        }
    } else {
        const int s0 = (id - 32) * 8;
#pragma unroll
        for (int q = 0; q < 8; ++q) As[q * 256 + tid] = enc[(size_t)(s0 + q) * 256 + tid];
        __syncthreads();
        const float* AVT = wsf + F_AVT;
        float* VB = wsf + F_VB;
        float bb = attB[tid];
        float acc[8] = {0.f, 0.f, 0.f, 0.f, 0.f, 0.f, 0.f, 0.f};
#pragma unroll 4
        for (int k = 0; k < 256; ++k) {
            float wv2 = AVT[(size_t)k * 256 + tid];
#pragma unroll
            for (int q = 0; q < 8; ++q) acc[q] = fmaf(As[q * 256 + k], wv2, acc[q]);
        }
#pragma unroll
        for (int q = 0; q < 8; ++q) VB[(size_t)(s0 + q) * 256 + tid] = acc[q] + bb;
    }
}

// ---------------------------------------------------------------------------
// mega roles
// ---------------------------------------------------------------------------
// h-WG: layer recurrence, 64 units, 8 lanes/unit (gate=j&3, khalf=j>>2)
__device__ __forceinline__ void role_h(
    int w, const float* __restrict__ Whh, const float* __restrict__ cin,
    const float* __restrict__ X1, u64* GX, u64* HPUB, unsigned* prog, float* hb)
{
    const int tid = threadIdx.x;
    const int ul = tid >> 3, j = tid & 7, kh = j >> 2;
    const int u = w * 64 + ul, row = (j & 3) * 256 + u;
    float4 wv[32];
    const float* wp = Whh + (size_t)row * 256 + kh * 128;
#pragma unroll
    for (int m = 0; m < 32; ++m) wv[m] = *(const float4*)(wp + 4 * m);
    float creg = (j == 0) ? cin[u] : 0.f;
    const int base = (tid & 63) & ~7;

    for (int t = 0; t < NSTEP; ++t) {
        if (tid < 256) hb[(t & 1) * 256 + tid] = pollval(HPUB + (size_t)t * 256 + tid, t + 1);
        float xv = 0.f;
        if (j < 4) xv = X1 ? X1[(size_t)t * 1024 + row]
                           : pollval(GX + ((t & 15) * 1024 + row), t + 1);
        __syncthreads();
        const float4* h4 = (const float4*)(hb + (t & 1) * 256);
        float a0 = 0.f, a1 = 0.f, a2 = 0.f, a3 = 0.f;
#pragma unroll
        for (int m = 0; m < 32; m += 4) {
            a0 = fma4(wv[m],     h4[kh * 32 + m],     a0);
            a1 = fma4(wv[m + 1], h4[kh * 32 + m + 1], a1);
            a2 = fma4(wv[m + 2], h4[kh * 32 + m + 2], a2);
            a3 = fma4(wv[m + 3], h4[kh * 32 + m + 3], a3);
        }
        float acc = (a0 + a1) + (a2 + a3);
        acc += __shfl_xor(acc, 4);       // combine K-halves
        acc += xv;                        // per-gate x (j<4 lanes)
        float gf = __shfl(acc, base + 1);
        float gg = __shfl(acc, base + 2);
        float go = __shfl(acc, base + 3);
        if (j == 0) {
            float cn = sigm(gf) * creg + sigm(acc) * tanh_(gg);
            creg = cn;
            tagstore(HPUB + (size_t)(t + 1) * 256 + u, sigm(go) * tanh_(cn), t + 2);
        }
        if (prog) {                       // L3: bump tail progress counter
            asm volatile("s_waitcnt vmcnt(0)" ::: "memory");
            __syncthreads();
            if (tid == 0)
                __hip_atomic_store(prog, (unsigned)(t + 2),
                                   __ATOMIC_RELAXED, __HIP_MEMORY_SCOPE_AGENT);
        }
    }
}

// x-WG: G[t] = Wih . h_src[t+1] + bias, published into depth-16 tagged ring
__device__ __forceinline__ void role_x(
    int w, const float* __restrict__ Wih, const float* __restrict__ bih,
    const float* __restrict__ bhh, u64* HSRC, u64* GXD, u64* HCONS, float* hb)
{
    const int tid = threadIdx.x;
    const int ul = tid >> 3, j = tid & 7, kh = j >> 2;
    const int u = w * 64 + ul, row = (j & 3) * 256 + u;
    float4 wv[32];
    const float* wp = Wih + (size_t)row * 256 + kh * 128;
#pragma unroll
    for (int m = 0; m < 32; ++m) wv[m] = *(const float4*)(wp + 4 * m);
    const float bias = bih[row] + bhh[row];

    if (tid < 256) hb[tid] = pollval(HSRC + 256 + tid, 2);   // h_src row 1
    __syncthreads();
    for (int t = 0; t < NSTEP; ++t) {
        float hn = 0.f;
        if (t < NSTEP - 1 && tid < 256)
            hn = pollval(HSRC + (size_t)(t + 2) * 256 + tid, t + 3);
        const float4* h4 = (const float4*)(hb + (t & 1) * 256);
        float a0 = 0.f, a1 = 0.f, a2 = 0.f, a3 = 0.f;
#pragma unroll
        for (int m = 0; m < 32; m += 4) {
            a0 = fma4(wv[m],     h4[kh * 32 + m],     a0);
            a1 = fma4(wv[m + 1], h4[kh * 32 + m + 1], a1);
            a2 = fma4(wv[m + 2], h4[kh * 32 + m + 2], a2);
            a3 = fma4(wv[m + 3], h4[kh * 32 + m + 3], a3);
        }
        float acc = (a0 + a1) + (a2 + a3);
        acc += __shfl_xor(acc, 4);
        if (j < 4) {
            // ring slot free? OWN consumer (unit u's h-WG) must be past t-16:
            // it publishes HCONS row t-15 (tag t-14) only after consuming
            // ring slot (t-16)&15 == (t&15). Guard on own u, not another WG's.
            if (t >= 16)
                pollval(HCONS + (size_t)(t - 15) * 256 + u, t - 14);
            tagstore(GXD + ((t & 15) * 1024 + row), acc + bias, t + 1);
        }
        if (t < NSTEP - 1 && tid < 256) hb[((t + 1) & 1) * 256 + tid] = hn;
        __syncthreads();
    }
}

__global__ __launch_bounds__(512, 2) void mega_kernel(
    const float* __restrict__ Whh1,
    const float* __restrict__ Wih2, const float* __restrict__ Whh2,
    const float* __restrict__ Wih3, const float* __restrict__ Whh3,
    const float* __restrict__ bih2, const float* __restrict__ bhh2,
    const float* __restrict__ bih3, const float* __restrict__ bhh3,
    const float* __restrict__ cin,  const float* __restrict__ av,
    const float* __restrict__ enc,
    const float* __restrict__ b1, const float* __restrict__ b2,
    const float* __restrict__ b3,
    float* __restrict__ wsf, float* __restrict__ out)
{
    __shared__ __align__(16) float smem[3456];
    const int tid = threadIdx.x, wg = blockIdx.x;
    const int wave = tid >> 6, wlane = tid & 63;

    u64* H0A = (u64*)(wsf + F_H0A);
    u64* H1A = (u64*)(wsf + F_H1A);
    u64* H2A = (u64*)(wsf + F_H2A);
    u64* G2X = (u64*)(wsf + F_G2X);
    u64* G3X = (u64*)(wsf + F_G3X);
    unsigned* PROG = (unsigned*)(wsf + F_PROG);

    if (wg < 4) {
        role_h(wg, Whh1, cin, wsf + F_X1, nullptr, H0A, nullptr, smem);
    } else if (wg < 8) {
        role_x(wg - 4, Wih2, bih2, bhh2, H0A, G2X, H1A, smem);
    } else if (wg < 12) {
        role_h(wg - 8, Whh2, cin + 256, nullptr, G2X, H1A, nullptr, smem);
    } else if (wg < 16) {
        role_x(wg - 12, Wih3, bih3, bhh3, H1A, G3X, H2A, smem);
    } else if (wg < NREC) {
        role_h(wg - 16, Whh3, cin + 512, nullptr, G3X, H2A, PROG + (wg - 16), smem);
    } else {
        // ---------------- tail: per-t attention + MLP ----------------------
        const float* VB  = wsf + F_VB;
        const float* W1T = wsf + F_W1T;
        const float* W2T = wsf + F_W2T;
        const float* W3T = wsf + F_W3T;
        const float* AWT = wsf + F_AWT;
        const int j = tid & 255, hf = tid >> 8;

        if (tid < 256) smem[T_AV + tid] = av[tid];

        for (int t = wg - NREC; t < NSTEP; t += NTAIL) {
            __syncthreads();
            // 1. gate on progress counters (cheap discovery), then tag-verified load
            if (tid < 4) {
                while (__hip_atomic_load(PROG + tid, __ATOMIC_RELAXED,
                                         __HIP_MEMORY_SCOPE_AGENT) < (unsigned)(t + 2))
                    __builtin_amdgcn_s_sleep(8);
            }
            asm volatile("" ::: "memory");
            __syncthreads();
            if (tid < 256)
                smem[T_H2 + tid] = pollval(H2A + (size_t)(t + 1) * 256 + tid, t + 2);
            __syncthreads();
            // 2. ws[j] = sum_k AWT[k][j] h2[k]
            {
                const float* wp = AWT + (size_t)(hf * 128) * 256 + j;
                const float* hp = smem + T_H2 + hf * 128;
                float p0 = 0.f, p1 = 0.f;
#pragma unroll 4
                for (int k = 0; k < 128; k += 2) {
                    p0 = fmaf(wp[k * 256], hp[k], p0);
                    p1 = fmaf(wp[(k + 1) * 256], hp[k + 1], p1);
                }
                smem[T_WSP + hf * 256 + j] = p0 + p1;
            }
            __syncthreads();
            if (tid < 256) smem[T_WS + tid] = smem[T_WSP + tid] + smem[T_WSP + 256 + tid];
            __syncthreads();
            // 3. e + exp (2 s per thread)
            {
                const float* avs_ = smem + T_AV;
                const float* ws_  = smem + T_WS;
#pragma unroll
                for (int rep = 0; rep < 2; ++rep) {
                    const int s = tid + rep * 512;
                    const float4* vb4 = (const float4*)(VB + (size_t)s * 256);
                    float e0 = 0.f, e1 = 0.f, e2 = 0.f, e3 = 0.f;
#pragma unroll 4
                    for (int q = 0; q < 64; ++q) {
                        float4 vb = vb4[q];
                        const int k = q * 4;
                        e0 = fmaf(avs_[k],     tanh_(ws_[k]     + vb.x), e0);
                        e1 = fmaf(avs_[k + 1], tanh_(ws_[k + 1] + vb.y), e1);
                        e2 = fmaf(avs_[k + 2], tanh_(ws_[k + 2] + vb.z), e2);
                        e3 = fmaf(avs_[k + 3], tanh_(ws_[k + 3] + vb.w), e3);
                    }
                    smem[T_EX + s] = __expf((e0 + e1) + (e2 + e3));
                }
            }
            __syncthreads();
            // 4. softmax denom
            {
                float sv = smem[T_EX + tid] + smem[T_EX + 512 + tid];
                sv += __shfl_xor(sv, 1);  sv += __shfl_xor(sv, 2);
                sv += __shfl_xor(sv, 4);  sv += __shfl_xor(sv, 8);
                sv += __shfl_xor(sv, 16); sv += __shfl_xor(sv, 32);
                if (wlane == 0) smem[T_RED + wave] = sv;
            }
            __syncthreads();
            if (tid == 0) {
                float sm = 0.f;
#pragma unroll
                for (int i = 0; i < 8; ++i) sm += smem[T_RED + i];
                smem[T_RED + 8] = __builtin_amdgcn_rcpf(sm);
            }
            __syncthreads();
            // 5. ctx partial over s-half
            {
                const float* ex_ = smem + T_EX + hf * 512;
                const float* ep  = enc + (size_t)(hf * 512) * 256 + j;
                float c0 = 0.f, c1 = 0.f, c2 = 0.f, c3 = 0.f;
#pragma unroll 2
                for (int s = 0; s < 512; s += 4) {
                    c0 = fmaf(ex_[s],     ep[(size_t)s * 256],       c0);
                    c1 = fmaf(ex_[s + 1], ep[(size_t)(s + 1) * 256], c1);
                    c2 = fmaf(ex_[s + 2], ep[(size_t)(s + 2) * 256], c2);
                    c3 = fmaf(ex_[s + 3], ep[(size_t)(s + 3) * 256], c3);
                }
                smem[T_WSP + hf * 256 + j] = (c0 + c1) + (c2 + c3);
            }
            __syncthreads();
            // 6. cat = [h2, ctx/sum]
            if (tid < 256) {
                smem[T_CAT + tid] = smem[T_H2 + tid];
                smem[T_CAT + 256 + tid] =
                    (smem[T_WSP + tid] + smem[T_WSP + 256 + tid]) * smem[T_RED + 8];
            }
            __syncthreads();
            // 7. mlp1
            {
                const float* wp = W1T + (size_t)(hf * 256) * 256 + j;
                const float* cp = smem + T_CAT + hf * 256;
                float p0 = 0.f, p1 = 0.f;
#pragma unroll 4
                for (int k = 0; k < 256; k += 2) {
                    p0 = fmaf(wp[(size_t)k * 256], cp[k], p0);
                    p1 = fmaf(wp[(size_t)(k + 1) * 256], cp[k + 1], p1);
                }
                smem[T_WSP + hf * 256 + j] = p0 + p1;
            }
            __syncthreads();
            if (tid < 256)
                smem[T_O1 + tid] =
                    fmaxf(b1[tid] + smem[T_WSP + tid] + smem[T_WSP + 256 + tid], 0.f);
            __syncthreads();
            // 8. mlp2
            {
                const float* wp = W2T + (size_t)(hf * 128) * 256 + j;
                const float* cp = smem + T_O1 + hf * 128;
                float p0 = 0.f, p1 = 0.f;
#pragma unroll 4
                for (int k = 0; k < 128; k += 2) {
                    p0 = fmaf(wp[(size_t)k * 256], cp[k], p0);
                    p1 = fmaf(wp[(size_t)(k + 1) * 256], cp[k + 1], p1);
                }
                smem[T_WSP + hf * 256 + j] = p0 + p1;
            }
            __syncthreads();
            if (tid < 256)
                smem[T_O2 + tid] =
                    fmaxf(b2[tid] + smem[T_WSP + tid] + smem[T_WSP + 256 + tid], 0.f);
            __syncthreads();
            // 9. mlp3 head
            if (tid < 8 * VOCAB) {
                const int jj = tid >> 3, l = tid & 7;
                const float* wp = W3T + (size_t)(l * 32) * VOCAB + jj;
                const float* vp = smem + T_O2 + l * 32;
                float p = 0.f;
#pragma unroll 4
                for (int k = 0; k < 32; ++k) p = fmaf(wp[(size_t)k * VOCAB], vp[k], p);
                p += __shfl_xor(p, 1); p += __shfl_xor(p, 2); p += __shfl_xor(p, 4);
                if (l == 0) out[t * VOCAB + jj] = b3[jj] + p;
            }
        }
    }
}

extern "C" void kernel_launch(void* const* d_in, const int* in_sizes, int n_in,
                              void* d_out, int out_size, void* d_ws, size_t ws_size,
                              hipStream_t stream)
{
    (void)in_sizes; (void)n_in; (void)out_size; (void)ws_size;
    const int*   Y    = (const int*)  d_in[0];
    const float* h    = (const float*)d_in[1];
    const float* c    = (const float*)d_in[2];
    const float* enc  = (const float*)d_in[3];
    const float* emb  = (const float*)d_in[4];
    const float* Wih1 = (const float*)d_in[5];
    const float* Whh1 = (const float*)d_in[6];
    const float* bih1 = (const float*)d_in[7];
    const float* bhh1 = (const float*)d_in[8];
    const float* Wih2 = (const float*)d_in[9];
    const float* Whh2 = (const float*)d_in[10];
    const float* bih2 = (const float*)d_in[11];
    const float* bhh2 = (const float*)d_in[12];
    const float* Wih3 = (const float*)d_in[13];
    const float* Whh3 = (const float*)d_in[14];
    const float* bih3 = (const float*)d_in[15];
    const float* bhh3 = (const float*)d_in[16];
    const float* av   = (const float*)d_in[17];
    const float* attW = (const float*)d_in[18];
    const float* attV = (const float*)d_in[19];
    const float* attB = (const float*)d_in[20];
    const float* w1   = (const float*)d_in[21];
    const float* b1   = (const float*)d_in[22];
    const float* w2   = (const float*)d_in[23];
    const float* b2   = (const float*)d_in[24];
    const float* w3   = (const float*)d_in[25];
    const float* b3   = (const float*)d_in[26];
    float* wsf = (float*)d_ws;
    float* out = (float*)d_out;

    prep0_kernel<<<593, 256, 0, stream>>>(Wih1, attV, w1, w2, w3, attW, h, wsf);
    prep1_kernel<<<160, 256, 0, stream>>>(Y, emb, bih1, bhh1, enc, attB, wsf);
    mega_kernel<<<NMEGA, 512, 0, stream>>>(Whh1, Wih2, Whh2, Wih3, Whh3,
                                           bih2, bhh2, bih3, bhh3,
                                           c, av, enc, b1, b2, b3, wsf, out);
}

// Round 7
// 794.553 us; speedup vs baseline: 1.1818x; 1.1818x over previous
//
#include <hip/hip_runtime.h>

// ---------------------------------------------------------------------------
// DecoderRNN: 256-step LSTM(3) + Bahdanau attention + MLP head, batch=1.
// Round 7: r4 geometry restored (40 recurrence WGs: 8xL1, 16xL2, 16xL3 with
// in-WG off-path x-gemv; 216 tail WGs) + weights in NAMED float4 registers
// (r4/r5b demoted arrays to scratch: VGPR 48/84 < needed 64/128), PROG-counter
// tail gating, single fast prep kernel (direct row-gemv X1/VB, no big transposes).
// ---------------------------------------------------------------------------

#define VOCAB  47
#define NSTEP  256
#define NREC   40
#define NTAIL  216
#define NMEGA  (NREC + NTAIL)

typedef unsigned long long u64;

// workspace layout (float offsets)
#define F_PROG  16                        // u32[16] L3 progress counters
#define F_H0A   64                        // u64[257][256] tagged h0 history
#define F_H1A   (F_H0A + 131584)
#define F_H2A   (F_H1A + 131584)
#define F_X1    (F_H2A + 131584)          // [256][1024] L1 input gates (+biases)
#define F_VB    (F_X1 + 262144)           // [1024][256] att_V@encT + att_b
#define F_W1T   (F_VB + 262144)           // [512][256]
#define F_W2T   (F_W1T + 131072)          // [256][256]
#define F_W3T   (F_W2T + 65536)           // [256][47]
#define F_AWT   (F_W3T + 12032)           // [256][256] att_W^T

// tail LDS carve (floats)
#define T_H2  0
#define T_WS  256
#define T_WSP 512
#define T_EX  1024
#define T_CAT 2048
#define T_O1  2560
#define T_O2  2816
#define T_AV  3072
#define T_RED 3328

__device__ __forceinline__ float fma4(float4 w, float4 h, float acc) {
    acc = fmaf(w.x, h.x, acc); acc = fmaf(w.y, h.y, acc);
    acc = fmaf(w.z, h.z, acc); acc = fmaf(w.w, h.w, acc);
    return acc;
}
__device__ __forceinline__ float sigm(float x) {
    return __builtin_amdgcn_rcpf(1.f + __expf(-x));
}
__device__ __forceinline__ float tanh_(float x) {
    float e = __expf(2.f * x);
    return 1.f - 2.f * __builtin_amdgcn_rcpf(e + 1.f);
}
__device__ __forceinline__ void tagstore(u64* p, float v, unsigned tag) {
    u64 pk = ((u64)tag << 32) | (u64)__float_as_uint(v);
    __hip_atomic_store(p, pk, __ATOMIC_RELAXED, __HIP_MEMORY_SCOPE_AGENT);
}
__device__ __forceinline__ float pollval(u64* p, unsigned tag) {
    u64 v;
    do { v = __hip_atomic_load(p, __ATOMIC_RELAXED, __HIP_MEMORY_SCOPE_AGENT); }
    while ((unsigned)(v >> 32) != tag);
    return __uint_as_float((unsigned)(v & 0xffffffffull));
}

// ---------------------------------------------------------------------------
// prep: 433 WGs x 256.
//   0..31   X1[t][j]  = dot(emb[Y[t]], Wih1[j]) + bih1[j] + bhh1[j]  (direct rows)
//   32..159 VB[s][j]  = dot(enc[s], attV[j]) + attB[j]               (direct rows)
//   160..287 w1^T -> W1T ; 288..351 w2^T -> W2T ; 352..367 w3^T -> W3T
//   368..431 attW^T -> AWT ; 432 init tags + PROG
// ---------------------------------------------------------------------------
__global__ __launch_bounds__(256) void prep_kernel(
    const int* __restrict__ Y, const float* __restrict__ emb,
    const float* __restrict__ Wih1, const float* __restrict__ bih1,
    const float* __restrict__ bhh1,
    const float* __restrict__ enc, const float* __restrict__ attV,
    const float* __restrict__ attB,
    const float* __restrict__ w1, const float* __restrict__ w2,
    const float* __restrict__ w3, const float* __restrict__ attW,
    const float* __restrict__ h, float* __restrict__ wsf)
{
    __shared__ __align__(16) float As[8 * 256];
    __shared__ int ys[8];
    const int id = blockIdx.x, tid = threadIdx.x;

    if (id < 32) {
        const int t0 = id * 8;
        if (tid < 8) ys[tid] = Y[t0 + tid];
        __syncthreads();
#pragma unroll
        for (int q = 0; q < 8; ++q) As[q * 256 + tid] = emb[(size_t)ys[q] * 256 + tid];
        __syncthreads();
        float* X1 = wsf + F_X1;
        for (int cch = 0; cch < 4; ++cch) {
            const int j = cch * 256 + tid;
            const float4* wr = (const float4*)(Wih1 + (size_t)j * 256);
            const float bb = bih1[j] + bhh1[j];
            float acc[8] = {0.f, 0.f, 0.f, 0.f, 0.f, 0.f, 0.f, 0.f};
#pragma unroll 2
            for (int k4 = 0; k4 < 64; ++k4) {
                float4 w = wr[k4];
                const int k = k4 * 4;
#pragma unroll
                for (int q = 0; q < 8; ++q) {
                    acc[q] = fmaf(w.x, As[q * 256 + k],     acc[q]);
                    acc[q] = fmaf(w.y, As[q * 256 + k + 1], acc[q]);
                    acc[q] = fmaf(w.z, As[q * 256 + k + 2], acc[q]);
                    acc[q] = fmaf(w.w, As[q * 256 + k + 3], acc[q]);
                }
            }
#pragma unroll
            for (int q = 0; q < 8; ++q) X1[(size_t)(t0 + q) * 1024 + j] = acc[q] + bb;
        }
    } else if (id < 160) {
        const int s0 = (id - 32) * 8;
#pragma unroll
        for (int q = 0; q < 8; ++q) As[q * 256 + tid] = enc[(size_t)(s0 + q) * 256 + tid];
        __syncthreads();
        float* VB = wsf + F_VB;
        const float4* wr = (const float4*)(attV + (size_t)tid * 256);
        const float bb = attB[tid];
        float acc[8] = {0.f, 0.f, 0.f, 0.f, 0.f, 0.f, 0.f, 0.f};
#pragma unroll 2
        for (int k4 = 0; k4 < 64; ++k4) {
            float4 w = wr[k4];
            const int k = k4 * 4;
#pragma unroll
            for (int q = 0; q < 8; ++q) {
                acc[q] = fmaf(w.x, As[q * 256 + k],     acc[q]);
                acc[q] = fmaf(w.y, As[q * 256 + k + 1], acc[q]);
                acc[q] = fmaf(w.z, As[q * 256 + k + 2], acc[q]);
                acc[q] = fmaf(w.w, As[q * 256 + k + 3], acc[q]);
            }
        }
#pragma unroll
        for (int q = 0; q < 8; ++q) VB[(size_t)(s0 + q) * 256 + tid] = acc[q] + bb;
    } else if (id < 432) {
        const float* in; float* out; int rows, cols, bxi, byi;
        if (id < 288)      { in = w1;   out = wsf + F_W1T; rows = 256;  cols = 512;
                             bxi = (id - 160) & 15; byi = (id - 160) >> 4; }
        else if (id < 352) { in = w2;   out = wsf + F_W2T; rows = 256;  cols = 256;
                             bxi = (id - 288) & 7;  byi = (id - 288) >> 3; }
        else if (id < 368) { in = w3;   out = wsf + F_W3T; rows = VOCAB; cols = 256;
                             bxi = (id - 352) & 7;  byi = (id - 352) >> 3; }
        else               { in = attW; out = wsf + F_AWT; rows = 256;  cols = 256;
                             bxi = (id - 368) & 7;  byi = (id - 368) >> 3; }
        float* tile = As;                 // reuse LDS as [32][33]
        const int tx = tid & 31, ty = tid >> 5;
        const int bx = bxi * 32, by = byi * 32;
        int x = bx + tx;
#pragma unroll
        for (int jj = ty; jj < 32; jj += 8) {
            int y = by + jj;
            if (x < cols && y < rows) tile[jj * 33 + tx] = in[(size_t)y * cols + x];
        }
        __syncthreads();
        x = by + tx;
#pragma unroll
        for (int jj = ty; jj < 32; jj += 8) {
            int y = bx + jj;
            if (x < rows && y < cols) out[(size_t)y * rows + x] = tile[tx * 33 + jj];
        }
    } else {
        tagstore((u64*)(wsf + F_H0A) + tid, h[tid],       1u);
        tagstore((u64*)(wsf + F_H1A) + tid, h[256 + tid], 1u);
        tagstore((u64*)(wsf + F_H2A) + tid, h[512 + tid], 1u);
        if (tid < 16) ((unsigned*)(wsf + F_PROG))[tid] = 1u;
    }
}

// ---------------------------------------------------------------------------
// mega kernel: WGs 0..7 L1 (32 units), 8..23 L2 (16 units), 24..39 L3 (16),
// 40..255 tail (per-t attention + MLP).  Weights in NAMED float4 registers.
// ---------------------------------------------------------------------------
__global__ __launch_bounds__(512, 2) void mega_kernel(
    const float* __restrict__ Whh1,
    const float* __restrict__ Wih2, const float* __restrict__ Whh2,
    const float* __restrict__ Wih3, const float* __restrict__ Whh3,
    const float* __restrict__ bih2, const float* __restrict__ bhh2,
    const float* __restrict__ bih3, const float* __restrict__ bhh3,
    const float* __restrict__ cin,  const float* __restrict__ av,
    const float* __restrict__ enc,
    const float* __restrict__ b1, const float* __restrict__ b2,
    const float* __restrict__ b3,
    float* __restrict__ wsf, float* __restrict__ out)
{
    __shared__ __align__(16) float smem[3456];
    const int tid = threadIdx.x, wg = blockIdx.x;
    const int wave = tid >> 6, wlane = tid & 63;

    u64* H0A = (u64*)(wsf + F_H0A);
    u64* H1A = (u64*)(wsf + F_H1A);
    u64* H2A = (u64*)(wsf + F_H2A);
    unsigned* PROG = (unsigned*)(wsf + F_PROG);

    if (wg < 8) {
        // ---------------- L1: 32 units/WG, 4 lanes per gate-row -------------
        const float* X1 = wsf + F_X1;
        const int ug = wlane >> 4, gate = (wlane >> 2) & 3, l4 = wlane & 3;
        const int u = wg * 32 + wave * 4 + ug;
        const int ju = gate * 256 + u;
        const float* wp = Whh1 + (size_t)ju * 256;
#define LQ(m) (*(const float4*)(wp + ((m) * 4 + l4) * 4))
        const float4 q00 = LQ(0),  q01 = LQ(1),  q02 = LQ(2),  q03 = LQ(3),
                     q04 = LQ(4),  q05 = LQ(5),  q06 = LQ(6),  q07 = LQ(7),
                     q08 = LQ(8),  q09 = LQ(9),  q10 = LQ(10), q11 = LQ(11),
                     q12 = LQ(12), q13 = LQ(13), q14 = LQ(14), q15 = LQ(15);
#undef LQ
        float creg = ((wlane & 15) == 0) ? cin[u] : 0.f;
        const int b16 = wlane & 48;
        float* hb = smem;                 // [2][256]
        float xv = (l4 == 0) ? X1[ju] : 0.f;

        for (int t = 0; t < NSTEP; ++t) {
            if (tid < 256)
                hb[(t & 1) * 256 + tid] = pollval(H0A + (size_t)t * 256 + tid, t + 1);
            __syncthreads();
            const float4* a4 = (const float4*)(hb + (t & 1) * 256);
            float a0 = xv, a1 = 0.f, a2 = 0.f, a3 = 0.f;
            a0 = fma4(q00, a4[ 0 + l4], a0); a1 = fma4(q01, a4[ 4 + l4], a1);
            a2 = fma4(q02, a4[ 8 + l4], a2); a3 = fma4(q03, a4[12 + l4], a3);
            a0 = fma4(q04, a4[16 + l4], a0); a1 = fma4(q05, a4[20 + l4], a1);
            a2 = fma4(q06, a4[24 + l4], a2); a3 = fma4(q07, a4[28 + l4], a3);
            a0 = fma4(q08, a4[32 + l4], a0); a1 = fma4(q09, a4[36 + l4], a1);
            a2 = fma4(q10, a4[40 + l4], a2); a3 = fma4(q11, a4[44 + l4], a3);
            a0 = fma4(q12, a4[48 + l4], a0); a1 = fma4(q13, a4[52 + l4], a1);
            a2 = fma4(q14, a4[56 + l4], a2); a3 = fma4(q15, a4[60 + l4], a3);
            float acc = (a0 + a1) + (a2 + a3);
            acc += __shfl_xor(acc, 1); acc += __shfl_xor(acc, 2);
            float gf = __shfl(acc, b16 + 4);
            float gg = __shfl(acc, b16 + 8);
            float go = __shfl(acc, b16 + 12);
            if ((wlane & 15) == 0) {
                float cn = sigm(gf) * creg + sigm(acc) * tanh_(gg);
                creg = cn;
                tagstore(H0A + (size_t)(t + 1) * 256 + u, sigm(go) * tanh_(cn), t + 2);
            }
            if (t < NSTEP - 1) xv = (l4 == 0) ? X1[(size_t)(t + 1) * 1024 + ju] : 0.f;
        }
    } else if (wg < NREC) {
        // ---------------- L2/L3: 16 units/WG, 8 lanes per gate-row ----------
        const int role = (wg < 24) ? 1 : 2;
        const int ug = wlane >> 5, gate = (wlane >> 3) & 3, l8 = wlane & 7;
        const int wgr = wg - (role == 1 ? 8 : 24);
        const int u = wgr * 16 + wave * 2 + ug;
        const int ju = gate * 256 + u;
        const float* wip = ((role == 1) ? Wih2 : Wih3) + (size_t)ju * 256;
        const float* whp = ((role == 1) ? Whh2 : Whh3) + (size_t)ju * 256;
#define LI(m) (*(const float4*)(wip + ((m) * 8 + l8) * 4))
#define LH(m) (*(const float4*)(whp + ((m) * 8 + l8) * 4))
        const float4 wi0 = LI(0), wi1 = LI(1), wi2 = LI(2), wi3 = LI(3),
                     wi4 = LI(4), wi5 = LI(5), wi6 = LI(6), wi7 = LI(7);
        const float4 wh0 = LH(0), wh1 = LH(1), wh2 = LH(2), wh3 = LH(3),
                     wh4 = LH(4), wh5 = LH(5), wh6 = LH(6), wh7 = LH(7);
#undef LI
#undef LH
        const float biasr = (l8 == 0)
            ? ((role == 1) ? (bih2[ju] + bhh2[ju]) : (bih3[ju] + bhh3[ju])) : 0.f;
        float creg = ((wlane & 31) == 0) ? cin[((role == 1) ? 256 : 512) + u] : 0.f;
        u64* Hup  = (role == 1) ? H0A : H1A;
        u64* Hown = (role == 1) ? H1A : H2A;
        unsigned* prog = (role == 2) ? (PROG + wgr) : nullptr;
        const int b32 = wlane & 32;
        float* hb = smem;                 // [2][256]
        float* xb = smem + 512;           // [2][256]

        if (tid < 256) xb[tid] = pollval(Hup + 256 + tid, 2);
        __syncthreads();
        float xacc;
        {
            const float4* x4 = (const float4*)xb;
            float a0 = 0.f, a1 = 0.f, a2 = 0.f, a3 = 0.f;
            a0 = fma4(wi0, x4[ 0 + l8], a0); a1 = fma4(wi1, x4[ 8 + l8], a1);
            a2 = fma4(wi2, x4[16 + l8], a2); a3 = fma4(wi3, x4[24 + l8], a3);
            a0 = fma4(wi4, x4[32 + l8], a0); a1 = fma4(wi5, x4[40 + l8], a1);
            a2 = fma4(wi6, x4[48 + l8], a2); a3 = fma4(wi7, x4[56 + l8], a3);
            xacc = (a0 + a1) + (a2 + a3);
        }

        for (int t = 0; t < NSTEP; ++t) {
            if (tid < 256)
                hb[(t & 1) * 256 + tid] = pollval(Hown + (size_t)t * 256 + tid, t + 1);
            __syncthreads();
            const float4* h4 = (const float4*)(hb + (t & 1) * 256);
            float a0 = xacc + biasr, a1 = 0.f, a2 = 0.f, a3 = 0.f;
            a0 = fma4(wh0, h4[ 0 + l8], a0); a1 = fma4(wh1, h4[ 8 + l8], a1);
            a2 = fma4(wh2, h4[16 + l8], a2); a3 = fma4(wh3, h4[24 + l8], a3);
            a0 = fma4(wh4, h4[32 + l8], a0); a1 = fma4(wh5, h4[40 + l8], a1);
            a2 = fma4(wh6, h4[48 + l8], a2); a3 = fma4(wh7, h4[56 + l8], a3);
            float acc = (a0 + a1) + (a2 + a3);
            acc += __shfl_xor(acc, 1); acc += __shfl_xor(acc, 2); acc += __shfl_xor(acc, 4);
            float gf = __shfl(acc, b32 + 8);
            float gg = __shfl(acc, b32 + 16);
            float go = __shfl(acc, b32 + 24);
            if ((wlane & 31) == 0) {
                float cn = sigm(gf) * creg + sigm(acc) * tanh_(gg);
                creg = cn;
                tagstore(Hown + (size_t)(t + 1) * 256 + u, sigm(go) * tanh_(cn), t + 2);
            }
            if (prog) {                   // L3: bump tail progress counter
                asm volatile("s_waitcnt vmcnt(0)" ::: "memory");
                __syncthreads();
                if (tid == 0)
                    __hip_atomic_store(prog, (unsigned)(t + 2),
                                       __ATOMIC_RELAXED, __HIP_MEMORY_SCOPE_AGENT);
            }
            if (t < NSTEP - 1) {          // off-critical-path x-gemv for t+1
                if (tid < 256)
                    xb[((t + 1) & 1) * 256 + tid] =
                        pollval(Hup + (size_t)(t + 2) * 256 + tid, t + 3);
                __syncthreads();
                const float4* x4 = (const float4*)(xb + ((t + 1) & 1) * 256);
                float a0 = 0.f, a1 = 0.f, a2 = 0.f, a3 = 0.f;
                a0 = fma4(wi0, x4[ 0 + l8], a0); a1 = fma4(wi1, x4[ 8 + l8], a1);
                a2 = fma4(wi2, x4[16 + l8], a2); a3 = fma4(wi3, x4[24 + l8], a3);
                a0 = fma4(wi4, x4[32 + l8], a0); a1 = fma4(wi5, x4[40 + l8], a1);
                a2 = fma4(wi6, x4[48 + l8], a2); a3 = fma4(wi7, x4[56 + l8], a3);
                xacc = (a0 + a1) + (a2 + a3);
            }
        }
    } else {
        // ---------------- tail: per-t attention + MLP ----------------------
        const float* VB  = wsf + F_VB;
        const float* W1T = wsf + F_W1T;
        const float* W2T = wsf + F_W2T;
        const float* W3T = wsf + F_W3T;
        const float* AWT = wsf + F_AWT;
        const int j = tid & 255, hf = tid >> 8;

        if (tid < 256) smem[T_AV + tid] = av[tid];

        for (int t = wg - NREC; t < NSTEP; t += NTAIL) {
            __syncthreads();
            // 1. gate on 16 progress counters, then tag-verified bulk load
            if (tid < 16) {
                while (__hip_atomic_load(PROG + tid, __ATOMIC_RELAXED,
                                         __HIP_MEMORY_SCOPE_AGENT) < (unsigned)(t + 2))
                    __builtin_amdgcn_s_sleep(8);
            }
            asm volatile("" ::: "memory");
            __syncthreads();
            if (tid < 256)
                smem[T_H2 + tid] = pollval(H2A + (size_t)(t + 1) * 256 + tid, t + 2);
            __syncthreads();
            // 2. ws[j] = sum_k AWT[k][j] h2[k]
            {
                const float* wp = AWT + (size_t)(hf * 128) * 256 + j;
                const float* hp = smem + T_H2 + hf * 128;
                float p0 = 0.f, p1 = 0.f;
#pragma unroll 4
                for (int k = 0; k < 128; k += 2) {
                    p0 = fmaf(wp[k * 256], hp[k], p0);
                    p1 = fmaf(wp[(k + 1) * 256], hp[k + 1], p1);
                }
                smem[T_WSP + hf * 256 + j] = p0 + p1;
            }
            __syncthreads();
            if (tid < 256) smem[T_WS + tid] = smem[T_WSP + tid] + smem[T_WSP + 256 + tid];
            __syncthreads();
            // 3. e + exp (2 s per thread)
            {
                const float* avs_ = smem + T_AV;
                const float* ws_  = smem + T_WS;
#pragma unroll
                for (int rep = 0; rep < 2; ++rep) {
                    const int s = tid + rep * 512;
                    const float4* vb4 = (const float4*)(VB + (size_t)s * 256);
                    float e0 = 0.f, e1 = 0.f, e2 = 0.f, e3 = 0.f;
#pragma unroll 4
                    for (int q = 0; q < 64; ++q) {
                        float4 vb = vb4[q];
                        const int k = q * 4;
                        e0 = fmaf(avs_[k],     tanh_(ws_[k]     + vb.x), e0);
                        e1 = fmaf(avs_[k + 1], tanh_(ws_[k + 1] + vb.y), e1);
                        e2 = fmaf(avs_[k + 2], tanh_(ws_[k + 2] + vb.z), e2);
                        e3 = fmaf(avs_[k + 3], tanh_(ws_[k + 3] + vb.w), e3);
                    }
                    smem[T_EX + s] = __expf((e0 + e1) + (e2 + e3));
                }
            }
            __syncthreads();
            // 4. softmax denom
            {
                float sv = smem[T_EX + tid] + smem[T_EX + 512 + tid];
                sv += __shfl_xor(sv, 1);  sv += __shfl_xor(sv, 2);
                sv += __shfl_xor(sv, 4);  sv += __shfl_xor(sv, 8);
                sv += __shfl_xor(sv, 16); sv += __shfl_xor(sv, 32);
                if (wlane == 0) smem[T_RED + wave] = sv;
            }
            __syncthreads();
            if (tid == 0) {
                float sm = 0.f;
#pragma unroll
                for (int i = 0; i < 8; ++i) sm += smem[T_RED + i];
                smem[T_RED + 8] = __builtin_amdgcn_rcpf(sm);
            }
            __syncthreads();
            // 5. ctx partial over s-half
            {
                const float* ex_ = smem + T_EX + hf * 512;
                const float* ep  = enc + (size_t)(hf * 512) * 256 + j;
                float c0 = 0.f, c1 = 0.f, c2 = 0.f, c3 = 0.f;
#pragma unroll 2
                for (int s = 0; s < 512; s += 4) {
                    c0 = fmaf(ex_[s],     ep[(size_t)s * 256],       c0);
                    c1 = fmaf(ex_[s + 1], ep[(size_t)(s + 1) * 256], c1);
                    c2 = fmaf(ex_[s + 2], ep[(size_t)(s + 2) * 256], c2);
                    c3 = fmaf(ex_[s + 3], ep[(size_t)(s + 3) * 256], c3);
                }
                smem[T_WSP + hf * 256 + j] = (c0 + c1) + (c2 + c3);
            }
            __syncthreads();
            // 6. cat = [h2, ctx/sum]
            if (tid < 256) {
                smem[T_CAT + tid] = smem[T_H2 + tid];
                smem[T_CAT + 256 + tid] =
                    (smem[T_WSP + tid] + smem[T_WSP + 256 + tid]) * smem[T_RED + 8];
            }
            __syncthreads();
            // 7. mlp1
            {
                const float* wp = W1T + (size_t)(hf * 256) * 256 + j;
                const float* cp = smem + T_CAT + hf * 256;
                float p0 = 0.f, p1 = 0.f;
#pragma unroll 4
                for (int k = 0; k < 256; k += 2) {
                    p0 = fmaf(wp[(size_t)k * 256], cp[k], p0);
                    p1 = fmaf(wp[(size_t)(k + 1) * 256], cp[k + 1], p1);
                }
                smem[T_WSP + hf * 256 + j] = p0 + p1;
            }
            __syncthreads();
            if (tid < 256)
                smem[T_O1 + tid] =
                    fmaxf(b1[tid] + smem[T_WSP + tid] + smem[T_WSP + 256 + tid], 0.f);
            __syncthreads();
            // 8. mlp2
            {
                const float* wp = W2T + (size_t)(hf * 128) * 256 + j;
                const float* cp = smem + T_O1 + hf * 128;
                float p0 = 0.f, p1 = 0.f;
#pragma unroll 4
                for (int k = 0; k < 128; k += 2) {
                    p0 = fmaf(wp[(size_t)k * 256], cp[k], p0);
                    p1 = fmaf(wp[(size_t)(k + 1) * 256], cp[k + 1], p1);
                }
                smem[T_WSP + hf * 256 + j] = p0 + p1;
            }
            __syncthreads();
            if (tid < 256)
                smem[T_O2 + tid] =
                    fmaxf(b2[tid] + smem[T_WSP + tid] + smem[T_WSP + 256 + tid], 0.f);
            __syncthreads();
            // 9. mlp3 head
            if (tid < 8 * VOCAB) {
                const int jj = tid >> 3, l = tid & 7;
                const float* wp = W3T + (size_t)(l * 32) * VOCAB + jj;
                const float* vp = smem + T_O2 + l * 32;
                float p = 0.f;
#pragma unroll 4
                for (int k = 0; k < 32; ++k) p = fmaf(wp[(size_t)k * VOCAB], vp[k], p);
                p += __shfl_xor(p, 1); p += __shfl_xor(p, 2); p += __shfl_xor(p, 4);
                if (l == 0) out[t * VOCAB + jj] = b3[jj] + p;
            }
        }
    }
}

extern "C" void kernel_launch(void* const* d_in, const int* in_sizes, int n_in,
                              void* d_out, int out_size, void* d_ws, size_t ws_size,
                              hipStream_t stream)
{
    (void)in_sizes; (void)n_in; (void)out_size; (void)ws_size;
    const int*   Y    = (const int*)  d_in[0];
    const float* h    = (const float*)d_in[1];
    const float* c    = (const float*)d_in[2];
    const float* enc  = (const float*)d_in[3];
    const float* emb  = (const float*)d_in[4];
    const float* Wih1 = (const float*)d_in[5];
    const float* Whh1 = (const float*)d_in[6];
    const float* bih1 = (const float*)d_in[7];
    const float* bhh1 = (const float*)d_in[8];
    const float* Wih2 = (const float*)d_in[9];
    const float* Whh2 = (const float*)d_in[10];
    const float* bih2 = (const float*)d_in[11];
    const float* bhh2 = (const float*)d_in[12];
    const float* Wih3 = (const float*)d_in[13];
    const float* Whh3 = (const float*)d_in[14];
    const float* bih3 = (const float*)d_in[15];
    const float* bhh3 = (const float*)d_in[16];
    const float* av   = (const float*)d_in[17];
    const float* attW = (const float*)d_in[18];
    const float* attV = (const float*)d_in[19];
    const float* attB = (const float*)d_in[20];
    const float* w1   = (const float*)d_in[21];
    const float* b1   = (const float*)d_in[22];
    const float* w2   = (const float*)d_in[23];
    const float* b2   = (const float*)d_in[24];
    const float* w3   = (const float*)d_in[25];
    const float* b3   = (const float*)d_in[26];
    float* wsf = (float*)d_ws;
    float* out = (float*)d_out;

    prep_kernel<<<433, 256, 0, stream>>>(Y, emb, Wih1, bih1, bhh1,
                                         enc, attV, attB,
                                         w1, w2, w3, attW, h, wsf);
    mega_kernel<<<NMEGA, 512, 0, stream>>>(Whh1, Wih2, Whh2, Wih3, Whh3,
                                           bih2, bhh2, bih3, bhh3,
                                           c, av, enc, b1, b2, b3, wsf, out);
}